// Round 3
// baseline (1643.210 us; speedup 1.0000x reference)
//
#include <hip/hip_runtime.h>
#include <hip/hip_bf16.h>

#define BB 8
#define CC 512
#define NN 1024   // H*W
#define NG 32
#define CPG 16
#define NH 8
#define HD 64
#define C3 1536

typedef __hip_bfloat16 bf16;

__device__ __forceinline__ float b2f(bf16 h) { return __bfloat162float(h); }
__device__ __forceinline__ bf16 f2b(float f) { return __float2bfloat16(f); }

// ---------------- GroupNorm: one block per (b, g); f32 in, bf16 out ----------------
__global__ __launch_bounds__(256) void gn_kernel(const float* __restrict__ x,
                                                 const float* __restrict__ gamma,
                                                 const float* __restrict__ beta,
                                                 bf16* __restrict__ xn) {
    const int GSZ = CPG * NN;  // 16384, contiguous per group
    int b = blockIdx.x >> 5;
    int g = blockIdx.x & 31;
    size_t base = ((size_t)b * CC + (size_t)g * CPG) * NN;
    int tid = threadIdx.x;
    float s = 0.f, s2 = 0.f;
    for (int i = tid; i < GSZ; i += 256) {
        float v = x[base + i];
        s += v; s2 += v * v;
    }
#pragma unroll
    for (int off = 32; off > 0; off >>= 1) {
        s  += __shfl_down(s, off, 64);
        s2 += __shfl_down(s2, off, 64);
    }
    __shared__ float rs[4], rs2[4], stat[2];
    int wid = tid >> 6, lane = tid & 63;
    if (lane == 0) { rs[wid] = s; rs2[wid] = s2; }
    __syncthreads();
    if (tid == 0) {
        float ts  = rs[0] + rs[1] + rs[2] + rs[3];
        float ts2 = rs2[0] + rs2[1] + rs2[2] + rs2[3];
        float mean = ts * (1.f / GSZ);
        float var  = ts2 * (1.f / GSZ) - mean * mean;
        stat[0] = mean;
        stat[1] = rsqrtf(var + 1e-5f);
    }
    __syncthreads();
    float mean = stat[0], inv = stat[1];
    for (int i = tid; i < GSZ; i += 256) {
        int c = g * CPG + (i >> 10);
        float v = (x[base + i] - mean) * inv;
        xn[base + i] = f2b(v * gamma[c] + beta[c]);
    }
}

// ---------------- QKV GEMM: out[b][o][n] = sum_c W[o][c]*xn[b][c][n] + bias[o]
// 64x64 tile, BK=16, 4x4 per thread, fp32 compute; xn bf16, w/bias f32, out bf16.
__global__ __launch_bounds__(256) void qkv_gemm(const bf16* __restrict__ xn,
                                                const float* __restrict__ w,
                                                const float* __restrict__ bias,
                                                bf16* __restrict__ out) {
    __shared__ alignas(16) float Wt[16][68];  // [k][o], +4 pad
    __shared__ alignas(16) float Xt[16][64];  // [k][n]
    int b  = blockIdx.z;
    int o0 = blockIdx.y * 64;
    int n0 = blockIdx.x * 64;
    int tid = threadIdx.x;
    int tx = tid & 15, ty = tid >> 4;
    float acc[4][4] = {};
    const bf16* xb = xn + (size_t)b * CC * NN;

    for (int k0 = 0; k0 < CC; k0 += 16) {
        {
            int j  = tid & 15;   // k
            int i0 = tid >> 4;   // o
#pragma unroll
            for (int r = 0; r < 4; ++r) {
                int i = i0 + r * 16;
                Wt[j][i] = w[(size_t)(o0 + i) * CC + k0 + j];
            }
        }
        {
            int i  = tid & 63;          // n
            int j0 = (tid >> 6) << 2;   // k
#pragma unroll
            for (int r = 0; r < 4; ++r) {
                int j = j0 + r;
                Xt[j][i] = b2f(xb[(size_t)(k0 + j) * NN + n0 + i]);
            }
        }
        __syncthreads();
#pragma unroll
        for (int kk = 0; kk < 16; ++kk) {
            float4 av = *(const float4*)&Wt[kk][ty << 2];
            float4 bv = *(const float4*)&Xt[kk][tx << 2];
            float aa[4] = {av.x, av.y, av.z, av.w};
            float bb[4] = {bv.x, bv.y, bv.z, bv.w};
#pragma unroll
            for (int i = 0; i < 4; ++i)
#pragma unroll
                for (int j = 0; j < 4; ++j)
                    acc[i][j] += aa[i] * bb[j];
        }
        __syncthreads();
    }
#pragma unroll
    for (int i = 0; i < 4; ++i) {
        int o = o0 + (ty << 2) + i;
        float bv = bias[o];
        size_t rowbase = ((size_t)b * C3 + o) * NN + n0 + (tx << 2);
#pragma unroll
        for (int j = 0; j < 4; ++j)
            out[rowbase + j] = f2b(acc[i][j] + bv);
    }
}

// ---------------- Attention: one block per (b, h, query) ----------------
__global__ __launch_bounds__(256) void attn_kernel(const bf16* __restrict__ qkv,
                                                   bf16* __restrict__ ao) {
    int idx = blockIdx.x;
    int nq = idx & (NN - 1);
    int h  = (idx >> 10) & (NH - 1);
    int b  = idx >> 13;
    const bf16* qb = qkv + ((size_t)b * C3 + (size_t)h * HD) * NN;
    const bf16* kb = qb + (size_t)CC * NN;
    const bf16* vb = qb + (size_t)2 * CC * NN;
    int tid = threadIdx.x;
    int wid = tid >> 6, lane = tid & 63;

    __shared__ float qv[HD];
    __shared__ float wred[4];
    __shared__ float wpart[4][HD];

    if (tid < HD) qv[tid] = b2f(qb[(size_t)tid * NN + nq]) * 0.125f;  // 1/sqrt(64)
    __syncthreads();

    // scores for m = tid + {0,256,512,768}
    float s0 = 0.f, s1 = 0.f, s2 = 0.f, s3 = 0.f;
#pragma unroll 8
    for (int c = 0; c < HD; ++c) {
        float q = qv[c];
        const bf16* kr = kb + (size_t)c * NN + tid;
        s0 += q * b2f(kr[0]);
        s1 += q * b2f(kr[256]);
        s2 += q * b2f(kr[512]);
        s3 += q * b2f(kr[768]);
    }
    // softmax max
    float mx = fmaxf(fmaxf(s0, s1), fmaxf(s2, s3));
#pragma unroll
    for (int off = 32; off > 0; off >>= 1) mx = fmaxf(mx, __shfl_down(mx, off, 64));
    if (lane == 0) wred[wid] = mx;
    __syncthreads();
    mx = fmaxf(fmaxf(wred[0], wred[1]), fmaxf(wred[2], wred[3]));
    __syncthreads();  // everyone done reading wred before reuse
    float p0 = __expf(s0 - mx), p1 = __expf(s1 - mx), p2 = __expf(s2 - mx), p3 = __expf(s3 - mx);
    float ls = p0 + p1 + p2 + p3;
#pragma unroll
    for (int off = 32; off > 0; off >>= 1) ls += __shfl_down(ls, off, 64);
    if (lane == 0) wred[wid] = ls;
    __syncthreads();
    float rinv = 1.f / (wred[0] + wred[1] + wred[2] + wred[3]);
    p0 *= rinv; p1 *= rinv; p2 *= rinv; p3 *= rinv;

    // out[c] = sum_m p[m] * v[c][m]
    for (int c = 0; c < HD; ++c) {
        const bf16* vr = vb + (size_t)c * NN + tid;
        float a = p0 * b2f(vr[0]) + p1 * b2f(vr[256]) + p2 * b2f(vr[512]) + p3 * b2f(vr[768]);
#pragma unroll
        for (int off = 32; off > 0; off >>= 1) a += __shfl_down(a, off, 64);
        if (lane == 0) wpart[wid][c] = a;
    }
    __syncthreads();
    if (tid < HD) {
        float o = wpart[0][tid] + wpart[1][tid] + wpart[2][tid] + wpart[3][tid];
        ao[((size_t)b * CC + (size_t)h * HD + tid) * NN + nq] = f2b(o);
    }
}

// ---------------- Proj GEMM + bias + residual; ain bf16, w/bias/xres f32, out f32 ----------------
__global__ __launch_bounds__(256) void proj_gemm(const bf16* __restrict__ ain,
                                                 const float* __restrict__ w,
                                                 const float* __restrict__ bias,
                                                 const float* __restrict__ xres,
                                                 float* __restrict__ out) {
    __shared__ alignas(16) float Wt[16][68];
    __shared__ alignas(16) float Xt[16][64];
    int b  = blockIdx.z;
    int o0 = blockIdx.y * 64;
    int n0 = blockIdx.x * 64;
    int tid = threadIdx.x;
    int tx = tid & 15, ty = tid >> 4;
    float acc[4][4] = {};
    const bf16* xb = ain + (size_t)b * CC * NN;

    for (int k0 = 0; k0 < CC; k0 += 16) {
        {
            int j  = tid & 15;
            int i0 = tid >> 4;
#pragma unroll
            for (int r = 0; r < 4; ++r) {
                int i = i0 + r * 16;
                Wt[j][i] = w[(size_t)(o0 + i) * CC + k0 + j];
            }
        }
        {
            int i  = tid & 63;
            int j0 = (tid >> 6) << 2;
#pragma unroll
            for (int r = 0; r < 4; ++r) {
                int j = j0 + r;
                Xt[j][i] = b2f(xb[(size_t)(k0 + j) * NN + n0 + i]);
            }
        }
        __syncthreads();
#pragma unroll
        for (int kk = 0; kk < 16; ++kk) {
            float4 av = *(const float4*)&Wt[kk][ty << 2];
            float4 bv = *(const float4*)&Xt[kk][tx << 2];
            float aa[4] = {av.x, av.y, av.z, av.w};
            float bb[4] = {bv.x, bv.y, bv.z, bv.w};
#pragma unroll
            for (int i = 0; i < 4; ++i)
#pragma unroll
                for (int j = 0; j < 4; ++j)
                    acc[i][j] += aa[i] * bb[j];
        }
        __syncthreads();
    }
#pragma unroll
    for (int i = 0; i < 4; ++i) {
        int o = o0 + (ty << 2) + i;
        float bv = bias[o];
        size_t rowbase = ((size_t)b * CC + o) * NN + n0 + (tx << 2);
#pragma unroll
        for (int j = 0; j < 4; ++j) {
            out[rowbase + j] = acc[i][j] + bv + xres[rowbase + j];
        }
    }
}

extern "C" void kernel_launch(void* const* d_in, const int* in_sizes, int n_in,
                              void* d_out, int out_size, void* d_ws, size_t ws_size,
                              hipStream_t stream) {
    const float* x      = (const float*)d_in[0];
    const float* gamma  = (const float*)d_in[1];
    const float* beta   = (const float*)d_in[2];
    const float* w_qkv  = (const float*)d_in[3];
    const float* b_qkv  = (const float*)d_in[4];
    const float* w_proj = (const float*)d_in[5];
    const float* b_proj = (const float*)d_in[6];
    float* out = (float*)d_out;

    // bf16 intermediates: xn 8 MB, qkv 24 MB; ao reuses xn (dead after qkv_gemm).
    bf16* xn  = (bf16*)d_ws;                      // 4,194,304 elems
    bf16* qkv = xn + (size_t)BB * CC * NN;        // 12,582,912 elems -> 32 MB total
    bf16* ao  = xn;                               // reuse

    gn_kernel<<<BB * NG, 256, 0, stream>>>(x, gamma, beta, xn);
    qkv_gemm<<<dim3(NN / 64, C3 / 64, BB), 256, 0, stream>>>(xn, w_qkv, b_qkv, qkv);
    attn_kernel<<<BB * NH * NN, 256, 0, stream>>>(qkv, ao);
    proj_gemm<<<dim3(NN / 64, CC / 64, BB), 256, 0, stream>>>(ao, w_proj, b_proj, x, out);
}

// Round 4
// 415.832 us; speedup vs baseline: 3.9516x; 3.9516x over previous
//
#include <hip/hip_runtime.h>
#include <hip/hip_bf16.h>

#define BB 8
#define CC 512
#define NN 1024   // H*W
#define NG 32
#define CPG 16
#define NH 8
#define HD 64
#define C3 1536

typedef __hip_bfloat16 bf16;
typedef unsigned short ushort_t;

typedef __attribute__((ext_vector_type(8))) short bf16x8;
typedef __attribute__((ext_vector_type(4))) float floatx4;

__device__ __forceinline__ float b2f(bf16 h) { return __bfloat162float(h); }
__device__ __forceinline__ bf16 f2b(float f) { return __float2bfloat16(f); }
__device__ __forceinline__ float us2f(ushort_t u) {
    union { unsigned int i; float f; } c; c.i = ((unsigned int)u) << 16; return c.f;
}
__device__ __forceinline__ ushort_t f2us(float f) {
    bf16 h = __float2bfloat16(f);
    return *(ushort_t*)&h;
}

// ---------------- GroupNorm: one block per (b, g); f32 in, bf16 out ----------------
__global__ __launch_bounds__(256) void gn_kernel(const float* __restrict__ x,
                                                 const float* __restrict__ gamma,
                                                 const float* __restrict__ beta,
                                                 bf16* __restrict__ xn) {
    const int GSZ = CPG * NN;  // 16384, contiguous per group
    int b = blockIdx.x >> 5;
    int g = blockIdx.x & 31;
    size_t base = ((size_t)b * CC + (size_t)g * CPG) * NN;
    int tid = threadIdx.x;
    float s = 0.f, s2 = 0.f;
    for (int i = tid; i < GSZ; i += 256) {
        float v = x[base + i];
        s += v; s2 += v * v;
    }
#pragma unroll
    for (int off = 32; off > 0; off >>= 1) {
        s  += __shfl_down(s, off, 64);
        s2 += __shfl_down(s2, off, 64);
    }
    __shared__ float rs[4], rs2[4], stat[2];
    int wid = tid >> 6, lane = tid & 63;
    if (lane == 0) { rs[wid] = s; rs2[wid] = s2; }
    __syncthreads();
    if (tid == 0) {
        float ts  = rs[0] + rs[1] + rs[2] + rs[3];
        float ts2 = rs2[0] + rs2[1] + rs2[2] + rs2[3];
        float mean = ts * (1.f / GSZ);
        float var  = ts2 * (1.f / GSZ) - mean * mean;
        stat[0] = mean;
        stat[1] = rsqrtf(var + 1e-5f);
    }
    __syncthreads();
    float mean = stat[0], inv = stat[1];
    for (int i = tid; i < GSZ; i += 256) {
        int c = g * CPG + (i >> 10);
        float v = (x[base + i] - mean) * inv;
        xn[base + i] = f2b(v * gamma[c] + beta[c]);
    }
}

// ---------------- QKV GEMM (unchanged from passing round) ----------------
__global__ __launch_bounds__(256) void qkv_gemm(const bf16* __restrict__ xn,
                                                const float* __restrict__ w,
                                                const float* __restrict__ bias,
                                                bf16* __restrict__ out) {
    __shared__ alignas(16) float Wt[16][68];
    __shared__ alignas(16) float Xt[16][64];
    int b  = blockIdx.z;
    int o0 = blockIdx.y * 64;
    int n0 = blockIdx.x * 64;
    int tid = threadIdx.x;
    int tx = tid & 15, ty = tid >> 4;
    float acc[4][4] = {};
    const bf16* xb = xn + (size_t)b * CC * NN;

    for (int k0 = 0; k0 < CC; k0 += 16) {
        {
            int j  = tid & 15;
            int i0 = tid >> 4;
#pragma unroll
            for (int r = 0; r < 4; ++r) {
                int i = i0 + r * 16;
                Wt[j][i] = w[(size_t)(o0 + i) * CC + k0 + j];
            }
        }
        {
            int i  = tid & 63;
            int j0 = (tid >> 6) << 2;
#pragma unroll
            for (int r = 0; r < 4; ++r) {
                int j = j0 + r;
                Xt[j][i] = b2f(xb[(size_t)(k0 + j) * NN + n0 + i]);
            }
        }
        __syncthreads();
#pragma unroll
        for (int kk = 0; kk < 16; ++kk) {
            float4 av = *(const float4*)&Wt[kk][ty << 2];
            float4 bv = *(const float4*)&Xt[kk][tx << 2];
            float aa[4] = {av.x, av.y, av.z, av.w};
            float bb[4] = {bv.x, bv.y, bv.z, bv.w};
#pragma unroll
            for (int i = 0; i < 4; ++i)
#pragma unroll
                for (int j = 0; j < 4; ++j)
                    acc[i][j] += aa[i] * bb[j];
        }
        __syncthreads();
    }
#pragma unroll
    for (int i = 0; i < 4; ++i) {
        int o = o0 + (ty << 2) + i;
        float bv = bias[o];
        size_t rowbase = ((size_t)b * C3 + o) * NN + n0 + (tx << 2);
#pragma unroll
        for (int j = 0; j < 4; ++j)
            out[rowbase + j] = f2b(acc[i][j] + bv);
    }
}

// ---------------- Flash attention: one block per (b, h, 64-query tile) ----------------
// MFMA 16x16x32 bf16. LDS row stride 72 shorts (144B): 16B-aligned ds_read_b128.
#define LDR 72
__global__ __launch_bounds__(256) void attn_kernel(const bf16* __restrict__ qkv,
                                                   bf16* __restrict__ ao) {
    __shared__ ushort_t smem[18432];  // 36 KB
    ushort_t* Qt = smem;              // [64 q][72]   (q-major, channel inner)
    ushort_t* Kt = smem + 4608;       // [64 key][72] (key-major, channel inner)
    ushort_t* Vn = smem + 9216;       // [64 c][72]   (channel-major, key inner)
    ushort_t* Pw = smem + 13824;      // 4 waves x [16 q][72] (key inner)
    ushort_t* Ost = Kt;               // reuse for epilogue: [64 c][72] (q inner)

    int qt = blockIdx.x;        // query tile 0..15
    int h  = blockIdx.y;
    int bi = blockIdx.z;
    int q0 = qt * 64;
    int tid = threadIdx.x;
    int wq = tid >> 6;          // wave id: owns queries wq*16..+15
    int l  = tid & 63;
    int ln = l & 15;
    int qd = (l >> 4) & 3;      // quad

    const ushort_t* qg = (const ushort_t*)qkv + ((size_t)bi * C3 + (size_t)h * HD) * NN;
    const ushort_t* kg = qg + (size_t)CC * NN;
    const ushort_t* vg = qg + (size_t)2 * CC * NN;

    int sc = tid >> 2;          // staging channel 0..63
    int so = (tid & 3) << 4;    // staging col offset 0,16,32,48

    // ---- stage Q transposed, pre-scaled by 1/8 (exact in bf16) ----
    {
        const ushort_t* src = qg + (size_t)sc * NN + q0 + so;
        ushort_t tmp[16];
        *(uint4*)tmp      = *(const uint4*)src;
        *(uint4*)(tmp + 8) = *(const uint4*)(src + 8);
#pragma unroll
        for (int j = 0; j < 16; ++j)
            Qt[(so + j) * LDR + sc] = f2us(us2f(tmp[j]) * 0.125f);
    }
    __syncthreads();

    // ---- per-wave Q A-frags (row = q = wq*16 + ln, k = channel) ----
    bf16x8 aq0 = *(const bf16x8*)&Qt[(wq * 16 + ln) * LDR + 0 * 32 + qd * 8];
    bf16x8 aq1 = *(const bf16x8*)&Qt[(wq * 16 + ln) * LDR + 1 * 32 + qd * 8];

    floatx4 O[4];
#pragma unroll
    for (int t = 0; t < 4; ++t) O[t] = (floatx4){0.f, 0.f, 0.f, 0.f};
    float mrow[4] = {-1e30f, -1e30f, -1e30f, -1e30f};
    float lrow[4] = {0.f, 0.f, 0.f, 0.f};

    ushort_t* Pme = Pw + wq * 16 * LDR;

    for (int it = 0; it < 16; ++it) {
        int m0 = it * 64;
        __syncthreads();  // previous iter's Kt/Vn reads complete
        // ---- stage K transposed ----
        {
            const ushort_t* src = kg + (size_t)sc * NN + m0 + so;
            ushort_t tmp[16];
            *(uint4*)tmp       = *(const uint4*)src;
            *(uint4*)(tmp + 8) = *(const uint4*)(src + 8);
#pragma unroll
            for (int j = 0; j < 16; ++j)
                Kt[(so + j) * LDR + sc] = tmp[j];
        }
        // ---- stage V natural ----
        {
            const ushort_t* src = vg + (size_t)sc * NN + m0 + so;
            *(uint4*)&Vn[sc * LDR + so]     = *(const uint4*)src;
            *(uint4*)&Vn[sc * LDR + so + 8] = *(const uint4*)(src + 8);
        }
        __syncthreads();

        // ---- S = Q^T K : 4 col-tiles of 16 keys ----
        floatx4 S[4];
#pragma unroll
        for (int t = 0; t < 4; ++t) {
            bf16x8 b0 = *(const bf16x8*)&Kt[(t * 16 + ln) * LDR + 0 * 32 + qd * 8];
            bf16x8 b1 = *(const bf16x8*)&Kt[(t * 16 + ln) * LDR + 1 * 32 + qd * 8];
            floatx4 acc = (floatx4){0.f, 0.f, 0.f, 0.f};
            acc = __builtin_amdgcn_mfma_f32_16x16x32_bf16(aq0, b0, acc, 0, 0, 0);
            acc = __builtin_amdgcn_mfma_f32_16x16x32_bf16(aq1, b1, acc, 0, 0, 0);
            S[t] = acc;
        }

        // ---- online softmax (C-layout: col=ln=key, row=qd*4+r=query) ----
        float mx[4], al[4], rsum[4];
#pragma unroll
        for (int r = 0; r < 4; ++r) {
            float v = fmaxf(fmaxf(S[0][r], S[1][r]), fmaxf(S[2][r], S[3][r]));
#pragma unroll
            for (int msk = 1; msk < 16; msk <<= 1)
                v = fmaxf(v, __shfl_xor(v, msk, 64));
            float mn = fmaxf(mrow[r], v);
            al[r] = __expf(mrow[r] - mn);
            mrow[r] = mn;
            rsum[r] = 0.f;
        }
#pragma unroll
        for (int t = 0; t < 4; ++t) {
#pragma unroll
            for (int r = 0; r < 4; ++r) {
                float p = __expf(S[t][r] - mrow[r]);
                rsum[r] += p;
                Pme[(qd * 4 + r) * LDR + t * 16 + ln] = f2us(p);
            }
        }
#pragma unroll
        for (int r = 0; r < 4; ++r) {
#pragma unroll
            for (int msk = 1; msk < 16; msk <<= 1)
                rsum[r] += __shfl_xor(rsum[r], msk, 64);
            lrow[r] = lrow[r] * al[r] + rsum[r];
#pragma unroll
            for (int t = 0; t < 4; ++t) O[t][r] *= al[r];
        }

        // ---- O += P * V^T ----
        bf16x8 pa0 = *(const bf16x8*)&Pme[ln * LDR + 0 * 32 + qd * 8];
        bf16x8 pa1 = *(const bf16x8*)&Pme[ln * LDR + 1 * 32 + qd * 8];
#pragma unroll
        for (int t = 0; t < 4; ++t) {
            bf16x8 v0 = *(const bf16x8*)&Vn[(t * 16 + ln) * LDR + 0 * 32 + qd * 8];
            bf16x8 v1 = *(const bf16x8*)&Vn[(t * 16 + ln) * LDR + 1 * 32 + qd * 8];
            O[t] = __builtin_amdgcn_mfma_f32_16x16x32_bf16(pa0, v0, O[t], 0, 0, 0);
            O[t] = __builtin_amdgcn_mfma_f32_16x16x32_bf16(pa1, v1, O[t], 0, 0, 0);
        }
    }

    // ---- epilogue: normalize, transpose through LDS, coalesced write ----
    __syncthreads();  // all Kt reads done; safe to reuse as Ost
    float inv[4];
#pragma unroll
    for (int r = 0; r < 4; ++r) inv[r] = 1.f / lrow[r];
#pragma unroll
    for (int t = 0; t < 4; ++t) {
#pragma unroll
        for (int r = 0; r < 4; ++r) {
            // O: row = q = wq*16 + qd*4 + r, col = c = t*16 + ln
            Ost[(t * 16 + ln) * LDR + wq * 16 + qd * 4 + r] = f2us(O[t][r] * inv[r]);
        }
    }
    __syncthreads();
    {
        ushort_t* dst = (ushort_t*)ao + ((size_t)bi * CC + (size_t)h * HD + sc) * NN + q0 + so;
        *(uint4*)dst       = *(const uint4*)&Ost[sc * LDR + so];
        *(uint4*)(dst + 8) = *(const uint4*)&Ost[sc * LDR + so + 8];
    }
}

// ---------------- Proj GEMM + bias + residual (unchanged from passing round) ----------------
__global__ __launch_bounds__(256) void proj_gemm(const bf16* __restrict__ ain,
                                                 const float* __restrict__ w,
                                                 const float* __restrict__ bias,
                                                 const float* __restrict__ xres,
                                                 float* __restrict__ out) {
    __shared__ alignas(16) float Wt[16][68];
    __shared__ alignas(16) float Xt[16][64];
    int b  = blockIdx.z;
    int o0 = blockIdx.y * 64;
    int n0 = blockIdx.x * 64;
    int tid = threadIdx.x;
    int tx = tid & 15, ty = tid >> 4;
    float acc[4][4] = {};
    const bf16* xb = ain + (size_t)b * CC * NN;

    for (int k0 = 0; k0 < CC; k0 += 16) {
        {
            int j  = tid & 15;
            int i0 = tid >> 4;
#pragma unroll
            for (int r = 0; r < 4; ++r) {
                int i = i0 + r * 16;
                Wt[j][i] = w[(size_t)(o0 + i) * CC + k0 + j];
            }
        }
        {
            int i  = tid & 63;
            int j0 = (tid >> 6) << 2;
#pragma unroll
            for (int r = 0; r < 4; ++r) {
                int j = j0 + r;
                Xt[j][i] = b2f(xb[(size_t)(k0 + j) * NN + n0 + i]);
            }
        }
        __syncthreads();
#pragma unroll
        for (int kk = 0; kk < 16; ++kk) {
            float4 av = *(const float4*)&Wt[kk][ty << 2];
            float4 bv = *(const float4*)&Xt[kk][tx << 2];
            float aa[4] = {av.x, av.y, av.z, av.w};
            float bb[4] = {bv.x, bv.y, bv.z, bv.w};
#pragma unroll
            for (int i = 0; i < 4; ++i)
#pragma unroll
                for (int j = 0; j < 4; ++j)
                    acc[i][j] += aa[i] * bb[j];
        }
        __syncthreads();
    }
#pragma unroll
    for (int i = 0; i < 4; ++i) {
        int o = o0 + (ty << 2) + i;
        float bv = bias[o];
        size_t rowbase = ((size_t)b * CC + o) * NN + n0 + (tx << 2);
#pragma unroll
        for (int j = 0; j < 4; ++j) {
            out[rowbase + j] = acc[i][j] + bv + xres[rowbase + j];
        }
    }
}

extern "C" void kernel_launch(void* const* d_in, const int* in_sizes, int n_in,
                              void* d_out, int out_size, void* d_ws, size_t ws_size,
                              hipStream_t stream) {
    const float* x      = (const float*)d_in[0];
    const float* gamma  = (const float*)d_in[1];
    const float* beta   = (const float*)d_in[2];
    const float* w_qkv  = (const float*)d_in[3];
    const float* b_qkv  = (const float*)d_in[4];
    const float* w_proj = (const float*)d_in[5];
    const float* b_proj = (const float*)d_in[6];
    float* out = (float*)d_out;

    // bf16 intermediates: xn 8 MB, qkv 24 MB; ao reuses xn (dead after qkv_gemm).
    bf16* xn  = (bf16*)d_ws;                      // 4,194,304 elems
    bf16* qkv = xn + (size_t)BB * CC * NN;        // 12,582,912 elems -> 32 MB total
    bf16* ao  = xn;                               // reuse

    gn_kernel<<<BB * NG, 256, 0, stream>>>(x, gamma, beta, xn);
    qkv_gemm<<<dim3(NN / 64, C3 / 64, BB), 256, 0, stream>>>(xn, w_qkv, b_qkv, qkv);
    attn_kernel<<<dim3(NN / 64, NH, BB), 256, 0, stream>>>(qkv, ao);
    proj_gemm<<<dim3(NN / 64, CC / 64, BB), 256, 0, stream>>>(ao, w_proj, b_proj, x, out);
}

// Round 5
// 219.612 us; speedup vs baseline: 7.4823x; 1.8935x over previous
//
#include <hip/hip_runtime.h>
#include <hip/hip_bf16.h>

#define BB 8
#define CC 512
#define NN 1024   // H*W
#define NG 32
#define CPG 16
#define NH 8
#define HD 64
#define C3 1536

typedef __hip_bfloat16 bf16;
typedef unsigned short ushort_t;

typedef __attribute__((ext_vector_type(8))) short bf16x8;
typedef __attribute__((ext_vector_type(8))) unsigned short ushortx8;
typedef __attribute__((ext_vector_type(4))) float floatx4;

__device__ __forceinline__ float b2f(bf16 h) { return __bfloat162float(h); }
__device__ __forceinline__ bf16 f2b(float f) { return __float2bfloat16(f); }
__device__ __forceinline__ float us2f(ushort_t u) {
    union { unsigned int i; float f; } c; c.i = ((unsigned int)u) << 16; return c.f;
}
__device__ __forceinline__ ushort_t f2us(float f) {
    bf16 h = __float2bfloat16(f);
    return *(ushort_t*)&h;
}

// ---------------- GroupNorm: one block per (b, g); f32 [c][n] in, bf16 xnT [n][c] out ----------------
__global__ __launch_bounds__(256) void gn_kernel(const float* __restrict__ x,
                                                 const float* __restrict__ gamma,
                                                 const float* __restrict__ beta,
                                                 bf16* __restrict__ xnT) {
    const int GSZ = CPG * NN;  // 16384, contiguous per group
    int b = blockIdx.x >> 5;
    int g = blockIdx.x & 31;
    size_t base = ((size_t)b * CC + (size_t)g * CPG) * NN;
    int tid = threadIdx.x;
    float s = 0.f, s2 = 0.f;
    for (int i = tid; i < GSZ; i += 256) {
        float v = x[base + i];
        s += v; s2 += v * v;
    }
#pragma unroll
    for (int off = 32; off > 0; off >>= 1) {
        s  += __shfl_down(s, off, 64);
        s2 += __shfl_down(s2, off, 64);
    }
    __shared__ float rs[4], rs2[4], stat[2];
    __shared__ ushort_t Lt[16][264];  // [c][n-chunk 256 + pad]
    int wid = tid >> 6, lane = tid & 63;
    if (lane == 0) { rs[wid] = s; rs2[wid] = s2; }
    __syncthreads();
    if (tid == 0) {
        float ts  = rs[0] + rs[1] + rs[2] + rs[3];
        float ts2 = rs2[0] + rs2[1] + rs2[2] + rs2[3];
        float mean = ts * (1.f / GSZ);
        float var  = ts2 * (1.f / GSZ) - mean * mean;
        stat[0] = mean;
        stat[1] = rsqrtf(var + 1e-5f);
    }
    __syncthreads();
    float mean = stat[0], inv = stat[1];

    int c_loc = tid >> 4;            // 0..15
    int nsp   = (tid & 15) * 16;     // n sub-span
    float ga = gamma[g * CPG + c_loc];
    float be = beta[g * CPG + c_loc];
    const float* srcrow = x + base + (size_t)c_loc * NN;

    for (int nc = 0; nc < 4; ++nc) {
        int nb = nc * 256 + nsp;
        float fv[16];
        *(float4*)(fv + 0)  = *(const float4*)(srcrow + nb + 0);
        *(float4*)(fv + 4)  = *(const float4*)(srcrow + nb + 4);
        *(float4*)(fv + 8)  = *(const float4*)(srcrow + nb + 8);
        *(float4*)(fv + 12) = *(const float4*)(srcrow + nb + 12);
        ushortx8 u0, u1;
#pragma unroll
        for (int j = 0; j < 8; ++j) {
            u0[j] = f2us((fv[j]     - mean) * inv * ga + be);
            u1[j] = f2us((fv[j + 8] - mean) * inv * ga + be);
        }
        *(ushortx8*)&Lt[c_loc][nsp]     = u0;
        *(ushortx8*)&Lt[c_loc][nsp + 8] = u1;
        __syncthreads();
        // transposed read: thread = n-local, read 16 c (conflict-free: lanes span banks)
        ushort_t o16[16];
#pragma unroll
        for (int c = 0; c < 16; ++c) o16[c] = Lt[c][tid];
        ushort_t* dst = (ushort_t*)xnT + ((size_t)b * NN + nc * 256 + tid) * CC + g * CPG;
        *(uint4*)dst       = *(const uint4*)(o16);
        *(uint4*)(dst + 8) = *(const uint4*)(o16 + 8);
        __syncthreads();
    }
}

// ---------------- QKV GEMM (MFMA): qkv[b][o][n] = sum_c W[o][c] * xnT[b][n][c] + bias[o]
// 128x128 tile, BK=32, 4 waves x (4x4 of 16x16x32). LDS row stride 40 shorts (80B).
#define GSTR 40
__global__ __launch_bounds__(256) void qkv_gemm(const bf16* __restrict__ xnT,
                                                const float* __restrict__ w,
                                                const float* __restrict__ bias,
                                                bf16* __restrict__ qkv) {
    __shared__ ushort_t Wl[128 * GSTR];  // [o][k]
    __shared__ ushort_t Xl[128 * GSTR];  // [n][k]
    int b  = blockIdx.z;
    int o0 = blockIdx.y * 128;
    int n0 = blockIdx.x * 128;
    int tid = threadIdx.x;
    int wv = tid >> 6, ln = tid & 15, qd = (tid >> 4) & 3;
    int wm = wv >> 1, wn = wv & 1;

    int srow = tid >> 1;
    int kh   = (tid & 1) * 16;
    const float* wp = w + (size_t)(o0 + srow) * CC;
    const ushort_t* xp = (const ushort_t*)xnT + ((size_t)b * NN + n0 + srow) * CC;

    floatx4 acc[4][4];
#pragma unroll
    for (int i = 0; i < 4; ++i)
#pragma unroll
        for (int j = 0; j < 4; ++j) acc[i][j] = (floatx4){0.f, 0.f, 0.f, 0.f};

    for (int k0 = 0; k0 < CC; k0 += 32) {
        // stage W (f32 -> bf16)
        {
            float fv[16];
            *(float4*)(fv + 0)  = *(const float4*)(wp + k0 + kh + 0);
            *(float4*)(fv + 4)  = *(const float4*)(wp + k0 + kh + 4);
            *(float4*)(fv + 8)  = *(const float4*)(wp + k0 + kh + 8);
            *(float4*)(fv + 12) = *(const float4*)(wp + k0 + kh + 12);
            ushortx8 u0, u1;
#pragma unroll
            for (int j = 0; j < 8; ++j) { u0[j] = f2us(fv[j]); u1[j] = f2us(fv[j + 8]); }
            *(ushortx8*)&Wl[srow * GSTR + kh]     = u0;
            *(ushortx8*)&Wl[srow * GSTR + kh + 8] = u1;
        }
        // stage X (bf16 direct)
        {
            uint4 x0 = *(const uint4*)(xp + k0 + kh);
            uint4 x1 = *(const uint4*)(xp + k0 + kh + 8);
            *(uint4*)&Xl[srow * GSTR + kh]     = x0;
            *(uint4*)&Xl[srow * GSTR + kh + 8] = x1;
        }
        __syncthreads();
        bf16x8 af[4], bf[4];
#pragma unroll
        for (int i = 0; i < 4; ++i)
            af[i] = *(const bf16x8*)&Wl[(wm * 64 + i * 16 + ln) * GSTR + qd * 8];
#pragma unroll
        for (int j = 0; j < 4; ++j)
            bf[j] = *(const bf16x8*)&Xl[(wn * 64 + j * 16 + ln) * GSTR + qd * 8];
#pragma unroll
        for (int i = 0; i < 4; ++i)
#pragma unroll
            for (int j = 0; j < 4; ++j)
                acc[i][j] = __builtin_amdgcn_mfma_f32_16x16x32_bf16(af[i], bf[j], acc[i][j], 0, 0, 0);
        __syncthreads();
    }

    // epilogue: D row=o (qd*4+r), col=n (ln)
#pragma unroll
    for (int i = 0; i < 4; ++i) {
#pragma unroll
        for (int r = 0; r < 4; ++r) {
            int o = o0 + wm * 64 + i * 16 + qd * 4 + r;
            float bb = bias[o];
            size_t rb = ((size_t)b * C3 + o) * NN + n0 + wn * 64 + ln;
#pragma unroll
            for (int j = 0; j < 4; ++j)
                qkv[rb + j * 16] = f2b(acc[i][j][r] + bb);
        }
    }
}

// ---------------- Flash attention: one block per (b, h, 64-query tile) ----------------
// Input qkv[b][o][n]; output aoT[b][n][c]. MFMA 16x16x32 bf16. LDS stride 72 shorts.
#define LDR 72
__global__ __launch_bounds__(256) void attn_kernel(const bf16* __restrict__ qkv,
                                                   bf16* __restrict__ aoT) {
    __shared__ ushort_t smem[18432];  // 36 KB
    ushort_t* Qt = smem;              // [64 q][72]   (q-major, channel inner)
    ushort_t* Kt = smem + 4608;       // [64 key][72] (key-major, channel inner)
    ushort_t* Vn = smem + 9216;       // [64 c][72]   (channel-major, key inner)
    ushort_t* Pw = smem + 13824;      // 4 waves x [16 q][72] (key inner)

    int qt = blockIdx.x;        // query tile 0..15
    int h  = blockIdx.y;
    int bi = blockIdx.z;
    int q0 = qt * 64;
    int tid = threadIdx.x;
    int wq = tid >> 6;          // wave id: owns queries wq*16..+15
    int l  = tid & 63;
    int ln = l & 15;
    int qd = (l >> 4) & 3;      // quad

    const ushort_t* qg = (const ushort_t*)qkv + ((size_t)bi * C3 + (size_t)h * HD) * NN;
    const ushort_t* kg = qg + (size_t)CC * NN;
    const ushort_t* vg = qg + (size_t)2 * CC * NN;

    int sc = tid >> 2;          // staging channel 0..63
    int so = (tid & 3) << 4;    // staging col offset 0,16,32,48

    // ---- stage Q transposed, pre-scaled by 1/8 (exact in bf16) ----
    {
        const ushort_t* src = qg + (size_t)sc * NN + q0 + so;
        ushort_t tmp[16];
        *(uint4*)tmp       = *(const uint4*)src;
        *(uint4*)(tmp + 8) = *(const uint4*)(src + 8);
#pragma unroll
        for (int j = 0; j < 16; ++j)
            Qt[(so + j) * LDR + sc] = f2us(us2f(tmp[j]) * 0.125f);
    }
    __syncthreads();

    // ---- per-wave Q A-frags (row = q = wq*16 + ln, k = channel) ----
    bf16x8 aq0 = *(const bf16x8*)&Qt[(wq * 16 + ln) * LDR + 0 * 32 + qd * 8];
    bf16x8 aq1 = *(const bf16x8*)&Qt[(wq * 16 + ln) * LDR + 1 * 32 + qd * 8];

    floatx4 O[4];
#pragma unroll
    for (int t = 0; t < 4; ++t) O[t] = (floatx4){0.f, 0.f, 0.f, 0.f};
    float mrow[4] = {-1e30f, -1e30f, -1e30f, -1e30f};
    float lrow[4] = {0.f, 0.f, 0.f, 0.f};

    ushort_t* Pme = Pw + wq * 16 * LDR;

    for (int it = 0; it < 16; ++it) {
        int m0 = it * 64;
        __syncthreads();  // previous iter's Kt/Vn reads complete
        // ---- stage K transposed ----
        {
            const ushort_t* src = kg + (size_t)sc * NN + m0 + so;
            ushort_t tmp[16];
            *(uint4*)tmp       = *(const uint4*)src;
            *(uint4*)(tmp + 8) = *(const uint4*)(src + 8);
#pragma unroll
            for (int j = 0; j < 16; ++j)
                Kt[(so + j) * LDR + sc] = tmp[j];
        }
        // ---- stage V natural ----
        {
            const ushort_t* src = vg + (size_t)sc * NN + m0 + so;
            *(uint4*)&Vn[sc * LDR + so]     = *(const uint4*)src;
            *(uint4*)&Vn[sc * LDR + so + 8] = *(const uint4*)(src + 8);
        }
        __syncthreads();

        // ---- S = Q^T K : 4 col-tiles of 16 keys ----
        floatx4 S[4];
#pragma unroll
        for (int t = 0; t < 4; ++t) {
            bf16x8 b0 = *(const bf16x8*)&Kt[(t * 16 + ln) * LDR + 0 * 32 + qd * 8];
            bf16x8 b1 = *(const bf16x8*)&Kt[(t * 16 + ln) * LDR + 1 * 32 + qd * 8];
            floatx4 acc = (floatx4){0.f, 0.f, 0.f, 0.f};
            acc = __builtin_amdgcn_mfma_f32_16x16x32_bf16(aq0, b0, acc, 0, 0, 0);
            acc = __builtin_amdgcn_mfma_f32_16x16x32_bf16(aq1, b1, acc, 0, 0, 0);
            S[t] = acc;
        }

        // ---- online softmax (C-layout: col=ln=key, row=qd*4+r=query) ----
        float al[4], rsum[4];
#pragma unroll
        for (int r = 0; r < 4; ++r) {
            float v = fmaxf(fmaxf(S[0][r], S[1][r]), fmaxf(S[2][r], S[3][r]));
#pragma unroll
            for (int msk = 1; msk < 16; msk <<= 1)
                v = fmaxf(v, __shfl_xor(v, msk, 64));
            float mn = fmaxf(mrow[r], v);
            al[r] = __expf(mrow[r] - mn);
            mrow[r] = mn;
            rsum[r] = 0.f;
        }
#pragma unroll
        for (int t = 0; t < 4; ++t) {
#pragma unroll
            for (int r = 0; r < 4; ++r) {
                float p = __expf(S[t][r] - mrow[r]);
                rsum[r] += p;
                Pme[(qd * 4 + r) * LDR + t * 16 + ln] = f2us(p);
            }
        }
#pragma unroll
        for (int r = 0; r < 4; ++r) {
#pragma unroll
            for (int msk = 1; msk < 16; msk <<= 1)
                rsum[r] += __shfl_xor(rsum[r], msk, 64);
            lrow[r] = lrow[r] * al[r] + rsum[r];
#pragma unroll
            for (int t = 0; t < 4; ++t) O[t][r] *= al[r];
        }

        // ---- O += P * V^T ----
        bf16x8 pa0 = *(const bf16x8*)&Pme[ln * LDR + 0 * 32 + qd * 8];
        bf16x8 pa1 = *(const bf16x8*)&Pme[ln * LDR + 1 * 32 + qd * 8];
#pragma unroll
        for (int t = 0; t < 4; ++t) {
            bf16x8 v0 = *(const bf16x8*)&Vn[(t * 16 + ln) * LDR + 0 * 32 + qd * 8];
            bf16x8 v1 = *(const bf16x8*)&Vn[(t * 16 + ln) * LDR + 1 * 32 + qd * 8];
            O[t] = __builtin_amdgcn_mfma_f32_16x16x32_bf16(pa0, v0, O[t], 0, 0, 0);
            O[t] = __builtin_amdgcn_mfma_f32_16x16x32_bf16(pa1, v1, O[t], 0, 0, 0);
        }
    }

    // ---- epilogue: normalize, direct store to aoT[b][n][c] (O natural layout) ----
    float inv[4];
#pragma unroll
    for (int r = 0; r < 4; ++r) inv[r] = 1.f / lrow[r];
#pragma unroll
    for (int t = 0; t < 4; ++t) {
#pragma unroll
        for (int r = 0; r < 4; ++r) {
            int n = q0 + wq * 16 + qd * 4 + r;
            ((ushort_t*)aoT)[((size_t)bi * NN + n) * CC + h * HD + t * 16 + ln] =
                f2us(O[t][r] * inv[r]);
        }
    }
}

// ---------------- Proj GEMM (MFMA) + bias + residual: out[b][c][n] f32 ----------------
__global__ __launch_bounds__(256) void proj_gemm(const bf16* __restrict__ aoT,
                                                 const float* __restrict__ w,
                                                 const float* __restrict__ bias,
                                                 const float* __restrict__ xres,
                                                 float* __restrict__ out) {
    __shared__ ushort_t Wl[128 * GSTR];  // [c_out][k]
    __shared__ ushort_t Xl[128 * GSTR];  // [n][k]
    int b  = blockIdx.z;
    int o0 = blockIdx.y * 128;
    int n0 = blockIdx.x * 128;
    int tid = threadIdx.x;
    int wv = tid >> 6, ln = tid & 15, qd = (tid >> 4) & 3;
    int wm = wv >> 1, wn = wv & 1;

    int srow = tid >> 1;
    int kh   = (tid & 1) * 16;
    const float* wp = w + (size_t)(o0 + srow) * CC;
    const ushort_t* xp = (const ushort_t*)aoT + ((size_t)b * NN + n0 + srow) * CC;

    floatx4 acc[4][4];
#pragma unroll
    for (int i = 0; i < 4; ++i)
#pragma unroll
        for (int j = 0; j < 4; ++j) acc[i][j] = (floatx4){0.f, 0.f, 0.f, 0.f};

    for (int k0 = 0; k0 < CC; k0 += 32) {
        {
            float fv[16];
            *(float4*)(fv + 0)  = *(const float4*)(wp + k0 + kh + 0);
            *(float4*)(fv + 4)  = *(const float4*)(wp + k0 + kh + 4);
            *(float4*)(fv + 8)  = *(const float4*)(wp + k0 + kh + 8);
            *(float4*)(fv + 12) = *(const float4*)(wp + k0 + kh + 12);
            ushortx8 u0, u1;
#pragma unroll
            for (int j = 0; j < 8; ++j) { u0[j] = f2us(fv[j]); u1[j] = f2us(fv[j + 8]); }
            *(ushortx8*)&Wl[srow * GSTR + kh]     = u0;
            *(ushortx8*)&Wl[srow * GSTR + kh + 8] = u1;
        }
        {
            uint4 x0 = *(const uint4*)(xp + k0 + kh);
            uint4 x1 = *(const uint4*)(xp + k0 + kh + 8);
            *(uint4*)&Xl[srow * GSTR + kh]     = x0;
            *(uint4*)&Xl[srow * GSTR + kh + 8] = x1;
        }
        __syncthreads();
        bf16x8 af[4], bf[4];
#pragma unroll
        for (int i = 0; i < 4; ++i)
            af[i] = *(const bf16x8*)&Wl[(wm * 64 + i * 16 + ln) * GSTR + qd * 8];
#pragma unroll
        for (int j = 0; j < 4; ++j)
            bf[j] = *(const bf16x8*)&Xl[(wn * 64 + j * 16 + ln) * GSTR + qd * 8];
#pragma unroll
        for (int i = 0; i < 4; ++i)
#pragma unroll
            for (int j = 0; j < 4; ++j)
                acc[i][j] = __builtin_amdgcn_mfma_f32_16x16x32_bf16(af[i], bf[j], acc[i][j], 0, 0, 0);
        __syncthreads();
    }

#pragma unroll
    for (int i = 0; i < 4; ++i) {
#pragma unroll
        for (int r = 0; r < 4; ++r) {
            int o = o0 + wm * 64 + i * 16 + qd * 4 + r;
            float bb = bias[o];
            size_t rb = ((size_t)b * CC + o) * NN + n0 + wn * 64 + ln;
#pragma unroll
            for (int j = 0; j < 4; ++j)
                out[rb + j * 16] = acc[i][j][r] + bb + xres[rb + j * 16];
        }
    }
}

extern "C" void kernel_launch(void* const* d_in, const int* in_sizes, int n_in,
                              void* d_out, int out_size, void* d_ws, size_t ws_size,
                              hipStream_t stream) {
    const float* x      = (const float*)d_in[0];
    const float* gamma  = (const float*)d_in[1];
    const float* beta   = (const float*)d_in[2];
    const float* w_qkv  = (const float*)d_in[3];
    const float* b_qkv  = (const float*)d_in[4];
    const float* w_proj = (const float*)d_in[5];
    const float* b_proj = (const float*)d_in[6];
    float* out = (float*)d_out;

    // bf16 intermediates: xnT 8 MB, qkv 24 MB; aoT reuses xnT (dead after qkv_gemm).
    bf16* xnT = (bf16*)d_ws;                      // [b][n][c]
    bf16* qkv = xnT + (size_t)BB * CC * NN;       // [b][o][n], 24 MB -> 32 MB total
    bf16* aoT = xnT;                              // [b][n][c], reuse

    gn_kernel<<<BB * NG, 256, 0, stream>>>(x, gamma, beta, xnT);
    qkv_gemm<<<dim3(NN / 128, C3 / 128, BB), 256, 0, stream>>>(xnT, w_qkv, b_qkv, qkv);
    attn_kernel<<<dim3(NN / 64, NH, BB), 256, 0, stream>>>(qkv, aoT);
    proj_gemm<<<dim3(NN / 128, CC / 128, BB), 256, 0, stream>>>(aoT, w_proj, b_proj, x, out);
}